// Round 1
// baseline (3183.172 us; speedup 1.0000x reference)
//
#include <hip/hip_runtime.h>
#include <math.h>

#define THREADS 256

__global__ __launch_bounds__(THREADS)
void fused_net(const float* __restrict__ x,
               const float* __restrict__ W1, const float* __restrict__ b1,
               const float* __restrict__ W4, const float* __restrict__ b4,
               const float* __restrict__ W2, const float* __restrict__ b2,
               const float* __restrict__ gum,
               float* __restrict__ out, int B)
{
    const int row = blockIdx.x * THREADS + threadIdx.x;
    if (row >= B) return;

    const float* xr   = x   + (size_t)row * 64;
    const float* grow = gum + (size_t)row * 320;
    float*       orow = out + (size_t)row * 384;

    // ---------------- Phase A: acc[i] = sum_k x[k]*W1[k][i]  (k rolled, rank-1)
    float acc[100];
    #pragma unroll
    for (int i = 0; i < 100; ++i) acc[i] = 0.0f;

    #pragma clang loop unroll(disable)
    for (int k = 0; k < 64; ++k) {
        const float xk = xr[k];
        const float* wr = W1 + k * 100;   // uniform address -> s_load
        #pragma unroll
        for (int i = 0; i < 100; ++i) acc[i] = fmaf(xk, wr[i], acc[i]);
    }

    // h1 -> per-thread scratch (read back dynamically in phase B, once each)
    float h1[100];
    #pragma unroll
    for (int i = 0; i < 100; ++i) h1[i] = tanhf(acc[i] + b1[i]);

    // ---------------- Phase B: acc[i] = sum_j h1[j]*W4[j][i]  (j rolled, rank-1)
    #pragma unroll
    for (int i = 0; i < 100; ++i) acc[i] = 0.0f;

    #pragma clang loop unroll(disable)
    for (int j = 0; j < 100; ++j) {
        const float hj = h1[j];
        const float* wr = W4 + j * 100;   // uniform -> s_load
        #pragma unroll
        for (int i = 0; i < 100; ++i) acc[i] = fmaf(hj, wr[i], acc[i]);
    }

    // h2 in-place in the same registers (all later uses are literal-indexed)
    #pragma unroll
    for (int i = 0; i < 100; ++i) acc[i] = tanhf(acc[i] + b4[i]);

    // ---------------- Phase C: y1 raw logits, chunks of 16, parked in out[]
    #pragma clang loop unroll(disable)
    for (int n0 = 0; n0 < 64; n0 += 16) {
        float o[16];
        #pragma unroll
        for (int j = 0; j < 16; ++j) o[j] = 0.0f;
        #pragma unroll
        for (int i = 0; i < 100; ++i) {
            const float* wr = W2 + i * 384 + n0;   // uniform -> s_load
            #pragma unroll
            for (int j = 0; j < 16; ++j) o[j] = fmaf(acc[i], wr[j], o[j]);
        }
        #pragma unroll
        for (int j = 0; j < 16; ++j) o[j] += b2[n0 + j];
        float4* dst = (float4*)(orow + n0);
        dst[0] = make_float4(o[0],  o[1],  o[2],  o[3]);
        dst[1] = make_float4(o[4],  o[5],  o[6],  o[7]);
        dst[2] = make_float4(o[8],  o[9],  o[10], o[11]);
        dst[3] = make_float4(o[12], o[13], o[14], o[15]);
    }

    // ---------------- Phase D: y2 one-hot, chunks of 10 (= 2 gumbel groups)
    #pragma clang loop unroll(disable)
    for (int n0 = 0; n0 < 320; n0 += 10) {
        float o[10];
        #pragma unroll
        for (int j = 0; j < 10; ++j) o[j] = 0.0f;
        #pragma unroll
        for (int i = 0; i < 100; ++i) {
            const float* wr = W2 + i * 384 + 64 + n0;   // uniform -> s_load
            #pragma unroll
            for (int j = 0; j < 10; ++j) o[j] = fmaf(acc[i], wr[j], o[j]);
        }
        #pragma unroll
        for (int g = 0; g < 2; ++g) {
            float z[5];
            #pragma unroll
            for (int j = 0; j < 5; ++j)
                z[j] = (o[g*5 + j] + b2[64 + n0 + g*5 + j]) + grow[n0 + g*5 + j];
            int best = 0; float bz = z[0];
            #pragma unroll
            for (int j = 1; j < 5; ++j) { if (z[j] > bz) { bz = z[j]; best = j; } }
            #pragma unroll
            for (int j = 0; j < 5; ++j) o[g*5 + j] = (j == best) ? 1.0f : 0.0f;
        }
        // offset 64+n0 floats from a 1536B-aligned row base: 256+40*n0 bytes, 16B-aligned
        float4* dst = (float4*)(orow + 64 + n0);
        dst[0] = make_float4(o[0], o[1], o[2], o[3]);
        dst[1] = make_float4(o[4], o[5], o[6], o[7]);
        *(float2*)(orow + 64 + n0 + 8) = make_float2(o[8], o[9]);
    }

    // ---------------- Phase E: softmax fixup of the parked y1 logits
    {
        float o1[64];
        float4* op = (float4*)orow;
        #pragma unroll
        for (int i = 0; i < 16; ++i) {
            float4 v = op[i];
            o1[4*i+0] = v.x; o1[4*i+1] = v.y; o1[4*i+2] = v.z; o1[4*i+3] = v.w;
        }
        float m = o1[0];
        #pragma unroll
        for (int i = 1; i < 64; ++i) m = fmaxf(m, o1[i]);
        float s = 0.0f;
        #pragma unroll
        for (int i = 0; i < 64; ++i) { o1[i] = expf(o1[i] - m); s += o1[i]; }
        const float r = 1.0f / s;
        #pragma unroll
        for (int i = 0; i < 16; ++i)
            op[i] = make_float4(o1[4*i+0]*r, o1[4*i+1]*r, o1[4*i+2]*r, o1[4*i+3]*r);
    }
}

extern "C" void kernel_launch(void* const* d_in, const int* in_sizes, int n_in,
                              void* d_out, int out_size, void* d_ws, size_t ws_size,
                              hipStream_t stream) {
    const float* x  = (const float*)d_in[0];
    const float* W1 = (const float*)d_in[1];
    const float* b1 = (const float*)d_in[2];
    const float* W4 = (const float*)d_in[3];
    const float* b4 = (const float*)d_in[4];
    const float* W2 = (const float*)d_in[5];
    const float* b2 = (const float*)d_in[6];
    const float* g  = (const float*)d_in[7];
    float* out = (float*)d_out;

    const int B = in_sizes[0] / 64;
    const int grid = (B + THREADS - 1) / THREADS;
    hipLaunchKernelGGL(fused_net, dim3(grid), dim3(THREADS), 0, stream,
                       x, W1, b1, W4, b4, W2, b2, g, out, B);
}

// Round 2
// 1725.565 us; speedup vs baseline: 1.8447x; 1.8447x over previous
//
#include <hip/hip_runtime.h>
#include <math.h>

#define THREADS 256
#define ROWS_MAX 80
#define PITCH 104   // floats; row stride 416 B, 16B-aligned => float4 LDS reads OK

__global__ __launch_bounds__(THREADS)
void fused_net(const float* __restrict__ x,
               const float* __restrict__ W1, const float* __restrict__ b1,
               const float* __restrict__ W4, const float* __restrict__ b4,
               const float* __restrict__ W2, const float* __restrict__ b2,
               const float* __restrict__ gum,
               float* __restrict__ out)
{
    __shared__ float wbuf[ROWS_MAX * PITCH];   // 33,280 B

    const int tid = threadIdx.x;
    const int row = blockIdx.x * THREADS + tid;   // grid sized exactly: no early return (barriers!)
    const float* xr   = x   + (size_t)row * 64;
    const float* grow = gum + (size_t)row * 320;
    float*       orow = out + (size_t)row * 384;

    // ================= Stage W1 [64][100] (natural layout) =================
    for (int e = tid; e < 64 * 100; e += THREADS) {
        int k = e / 100, i = e - k * 100;
        wbuf[k * PITCH + i] = W1[e];             // coalesced read, broadcast-read later
    }
    __syncthreads();

    // ================= Phase A: rank-1  acc[i] += x[k]*W1[k][i] ============
    float acc[100];
    #pragma unroll
    for (int i = 0; i < 100; ++i) acc[i] = 0.f;

    float xk = xr[0];
    #pragma clang loop unroll(disable)
    for (int k = 0; k < 64; ++k) {
        float xn = xr[(k + 1) & 63];             // distance-1 prefetch, always in-bounds
        const float4* wr = (const float4*)&wbuf[k * PITCH];
        #pragma unroll
        for (int q = 0; q < 25; ++q) {
            float4 w = wr[q];
            acc[4*q+0] = fmaf(xk, w.x, acc[4*q+0]);
            acc[4*q+1] = fmaf(xk, w.y, acc[4*q+1]);
            acc[4*q+2] = fmaf(xk, w.z, acc[4*q+2]);
            acc[4*q+3] = fmaf(xk, w.w, acc[4*q+3]);
        }
        xk = xn;
    }
    #pragma unroll
    for (int i = 0; i < 100; ++i) acc[i] = tanhf(acc[i] + b1[i]);
    // acc[] now holds h1, literal-indexed registers only

    // ====== Phase B: h2[i] = tanh(dot(h1, W4[:,i]) + b4[i]) -> park out[64+i]
    {
        int c0 = 0;
        #pragma clang loop unroll(disable)
        for (int chunk = 0; chunk < 2; ++chunk) {
            const int rows = (chunk == 0) ? 80 : 20;
            __syncthreads();                      // prior readers of wbuf done
            for (int e = tid; e < rows * 100; e += THREADS) {
                int r = e % rows, j = e / rows;   // consecutive tid -> consecutive r (coalesced)
                wbuf[r * PITCH + j] = W4[j * 100 + c0 + r];  // transposed into LDS
            }
            __syncthreads();
            #pragma clang loop unroll(disable)
            for (int il = 0; il < rows; ++il) {
                const float4* wr = (const float4*)&wbuf[il * PITCH];
                float s0 = 0.f, s1 = 0.f, s2 = 0.f, s3 = 0.f;
                #pragma unroll
                for (int q = 0; q < 25; ++q) {
                    float4 w = wr[q];
                    s0 = fmaf(acc[4*q+0], w.x, s0);
                    s1 = fmaf(acc[4*q+1], w.y, s1);
                    s2 = fmaf(acc[4*q+2], w.z, s2);
                    s3 = fmaf(acc[4*q+3], w.w, s3);
                }
                float h2 = tanhf(((s0 + s1) + (s2 + s3)) + b4[c0 + il]);
                orow[64 + c0 + il] = h2;          // park in this row's own out slice
            }
            c0 += rows;
        }
    }

    // h1 dead; read h2 back into literal-indexed registers (same-thread RAW, ordered)
    float h2r[100];
    #pragma unroll
    for (int i = 0; i < 100; ++i) h2r[i] = orow[64 + i];

    // ================= Phase C: y1 logits (park) + running max ==============
    __syncthreads();
    for (int e = tid; e < 64 * 100; e += THREADS) {
        int n = e & 63, i = e >> 6;
        wbuf[n * PITCH + i] = W2[i * 384 + n];   // W2 cols 0..63, transposed
    }
    __syncthreads();

    float m = -1e30f;
    #pragma clang loop unroll(disable)
    for (int n = 0; n < 64; ++n) {
        const float4* wr = (const float4*)&wbuf[n * PITCH];
        float s0 = 0.f, s1 = 0.f, s2 = 0.f, s3 = 0.f;
        #pragma unroll
        for (int q = 0; q < 25; ++q) {
            float4 w = wr[q];
            s0 = fmaf(h2r[4*q+0], w.x, s0);
            s1 = fmaf(h2r[4*q+1], w.y, s1);
            s2 = fmaf(h2r[4*q+2], w.z, s2);
            s3 = fmaf(h2r[4*q+3], w.w, s3);
        }
        float z = ((s0 + s1) + (s2 + s3)) + b2[n];
        m = fmaxf(m, z);
        orow[n] = z;                              // park logit
    }
    // softmax fixup while lines are L1-hot (exp recomputed in pass 2, identical rounding)
    {
        float ssum = 0.f;
        #pragma clang loop unroll(disable)
        for (int n = 0; n < 64; ++n) ssum += expf(orow[n] - m);
        const float rinv = 1.f / ssum;
        #pragma clang loop unroll(disable)
        for (int n = 0; n < 64; ++n) orow[n] = expf(orow[n] - m) * rinv;
    }

    // ================= Phase D: straight-through one-hot ====================
    // forward value of y_soft + (y_hard - y_soft) is exactly one_hot(argmax(z+g))
    float gcur[5];
    #pragma unroll
    for (int jj = 0; jj < 5; ++jj) gcur[jj] = grow[jj];   // preload group 0

    #pragma clang loop unroll(disable)
    for (int chunk = 0; chunk < 4; ++chunk) {
        const int r0 = 64 + chunk * 80;          // W2 col base (80 cols = 16 groups, group-aligned)
        __syncthreads();
        for (int e = tid; e < 80 * 100; e += THREADS) {
            int n = e % 80, i = e / 80;
            wbuf[n * PITCH + i] = W2[i * 384 + r0 + n];
        }
        __syncthreads();
        const int g0 = chunk * 16;
        #pragma clang loop unroll(disable)
        for (int g = 0; g < 16; ++g) {
            // prefetch next group's gumbel (wraps to group 0 at the end; always in-bounds)
            const float* gpn = grow + (((g0 + g + 1) & 63) * 5);
            float gnext[5];
            #pragma unroll
            for (int jj = 0; jj < 5; ++jj) gnext[jj] = gpn[jj];

            float z[5];
            #pragma unroll
            for (int jj = 0; jj < 5; ++jj) {
                const float4* wr = (const float4*)&wbuf[(g * 5 + jj) * PITCH];
                float s0 = 0.f, s1 = 0.f, s2 = 0.f, s3 = 0.f;
                #pragma unroll
                for (int q = 0; q < 25; ++q) {
                    float4 w = wr[q];
                    s0 = fmaf(h2r[4*q+0], w.x, s0);
                    s1 = fmaf(h2r[4*q+1], w.y, s1);
                    s2 = fmaf(h2r[4*q+2], w.z, s2);
                    s3 = fmaf(h2r[4*q+3], w.w, s3);
                }
                z[jj] = (((s0 + s1) + (s2 + s3)) + b2[r0 + g * 5 + jj]) + gcur[jj];
            }
            int best = 0; float bz = z[0];
            #pragma unroll
            for (int jj = 1; jj < 5; ++jj) { if (z[jj] > bz) { bz = z[jj]; best = jj; } }
            float* op = orow + r0 + g * 5;
            #pragma unroll
            for (int jj = 0; jj < 5; ++jj) op[jj] = (jj == best) ? 1.f : 0.f;

            #pragma unroll
            for (int jj = 0; jj < 5; ++jj) gcur[jj] = gnext[jj];
        }
    }
}

extern "C" void kernel_launch(void* const* d_in, const int* in_sizes, int n_in,
                              void* d_out, int out_size, void* d_ws, size_t ws_size,
                              hipStream_t stream) {
    const float* x  = (const float*)d_in[0];
    const float* W1 = (const float*)d_in[1];
    const float* b1 = (const float*)d_in[2];
    const float* W4 = (const float*)d_in[3];
    const float* b4 = (const float*)d_in[4];
    const float* W2 = (const float*)d_in[5];
    const float* b2 = (const float*)d_in[6];
    const float* g  = (const float*)d_in[7];
    float* out = (float*)d_out;

    const int B = in_sizes[0] / 64;              // 262144
    const int grid = B / THREADS;                // exact: 1024 blocks
    hipLaunchKernelGGL(fused_net, dim3(grid), dim3(THREADS), 0, stream,
                       x, W1, b1, W4, b4, W2, b2, g, out);
}